// Round 1
// baseline (2143.591 us; speedup 1.0000x reference)
//
#include <hip/hip_runtime.h>
#include <math.h>

typedef unsigned short u16;
typedef unsigned int u32;
typedef float f4 __attribute__((ext_vector_type(4)));
typedef short bf16x8 __attribute__((ext_vector_type(8)));
typedef float f32x4 __attribute__((ext_vector_type(4)));

#define S_LEN 2048
#define H_DIM 2880
#define NQD 4096
#define RANKD 384
#define HD 64
#define NH 64
#define NKV 8
#define RLN 0.37244970541f  /* ln(150000)/32 */

__device__ __forceinline__ u16 f2bf(float f) {
  u32 u = __float_as_uint(f);
  u += 0x7fffu + ((u >> 16) & 1u);
  return (u16)(u >> 16);
}

// ---------------- fp32 -> bf16 convert ----------------
__global__ void conv_f2b(const float* __restrict__ in, u16* __restrict__ out, int n4) {
  int i = blockIdx.x * blockDim.x + threadIdx.x;
  if (i >= n4) return;
  f4 v = ((const f4*)in)[i];
  ushort4 o;
  o.x = f2bf(v[0]); o.y = f2bf(v[1]); o.z = f2bf(v[2]); o.w = f2bf(v[3]);
  ((ushort4*)out)[i] = o;
}

// ---------------- bf16 MFMA GEMM:  C(MxN) = A(MxK) @ W(NxK)^T (+bias) ----------------
// mode 0: fp32 row-major out0 (+bias)
// mode 1: Q: RoPE, write bf16 out0[(head*S + s)*64 + d], head = n0/64
// mode 2: KV: even n-tiles = K half (RoPE -> out0), odd = V half (plain -> out1), kvh = n0/128
// mode 3: bf16 row-major out0
__global__ __launch_bounds__(256) void gemm_bt(
    const u16* __restrict__ A, const u16* __restrict__ W,
    const float* __restrict__ bias,
    int M, int N, int K, int mode,
    void* __restrict__ out0, void* __restrict__ out1) {
  __shared__ __align__(16) u16 As[64 * 32];
  __shared__ __align__(16) u16 Bs[64 * 32];
  int t = threadIdx.x;
  int m0 = blockIdx.x * 64, n0 = blockIdx.y * 64;
  int w = t >> 6, L = t & 63;
  int srow = t >> 2, scol = (t & 3) * 8;
  int lm = L & 15, quad = L >> 4;
  const u16* Ap = A + (size_t)(m0 + srow) * K + scol;
  const u16* Wp = W + (size_t)(n0 + srow) * K + scol;
  f32x4 acc0 = {0.f, 0.f, 0.f, 0.f}, acc1 = acc0, acc2 = acc0, acc3 = acc0;
  int aoff = (w * 16 + lm) * 32 + quad * 8;
  int boff = lm * 32 + quad * 8;
  int nk = K >> 5;
  uint4 av = *(const uint4*)Ap;
  uint4 wv = *(const uint4*)Wp;
  for (int kt = 0; kt < nk; ++kt) {
    *(uint4*)&As[srow * 32 + scol] = av;
    *(uint4*)&Bs[srow * 32 + scol] = wv;
    __syncthreads();
    if (kt + 1 < nk) {
      Ap += 32; Wp += 32;
      av = *(const uint4*)Ap;
      wv = *(const uint4*)Wp;
    }
    bf16x8 af = *(const bf16x8*)&As[aoff];
    bf16x8 b0 = *(const bf16x8*)&Bs[boff];
    bf16x8 b1 = *(const bf16x8*)&Bs[boff + 16 * 32];
    bf16x8 b2 = *(const bf16x8*)&Bs[boff + 32 * 32];
    bf16x8 b3 = *(const bf16x8*)&Bs[boff + 48 * 32];
    acc0 = __builtin_amdgcn_mfma_f32_16x16x32_bf16(af, b0, acc0, 0, 0, 0);
    acc1 = __builtin_amdgcn_mfma_f32_16x16x32_bf16(af, b1, acc1, 0, 0, 0);
    acc2 = __builtin_amdgcn_mfma_f32_16x16x32_bf16(af, b2, acc2, 0, 0, 0);
    acc3 = __builtin_amdgcn_mfma_f32_16x16x32_bf16(af, b3, acc3, 0, 0, 0);
    __syncthreads();
  }
  int mbase = m0 + w * 16 + quad * 4;
  if (mode == 0) {
    float* outF = (float*)out0;
    for (int r = 0; r < 4; ++r) {
      int row = mbase + r;
      float vals[4] = {acc0[r], acc1[r], acc2[r], acc3[r]};
      for (int nt = 0; nt < 4; ++nt) {
        int col = n0 + nt * 16 + lm;
        float v = vals[nt];
        if (bias) v += bias[col];
        outF[(size_t)row * N + col] = v;
      }
    }
  } else if (mode == 3) {
    u16* outB = (u16*)out0;
    for (int r = 0; r < 4; ++r) {
      int row = mbase + r;
      float vals[4] = {acc0[r], acc1[r], acc2[r], acc3[r]};
      for (int nt = 0; nt < 4; ++nt) {
        int col = n0 + nt * 16 + lm;
        float v = vals[nt];
        if (bias) v += bias[col];
        outB[(size_t)row * N + col] = f2bf(v);
      }
    }
  } else {
    bool isV = (mode == 2) && ((blockIdx.y & 1) == 1);
    int head = (mode == 1) ? (n0 >> 6) : (n0 >> 7);
    if (isV) {
      u16* outB = (u16*)out1;
      for (int r = 0; r < 4; ++r) {
        int s = mbase + r;
        float vals[4] = {acc0[r], acc1[r], acc2[r], acc3[r]};
        u16* op = outB + ((size_t)head * S_LEN + s) * HD;
        for (int nt = 0; nt < 4; ++nt) op[nt * 16 + lm] = f2bf(vals[nt]);
      }
    } else {
      u16* outB = (u16*)out0;
      float invf1 = __expf(-(float)lm * RLN);
      float invf2 = __expf(-(float)(lm + 16) * RLN);
      for (int r = 0; r < 4; ++r) {
        int s = mbase + r;
        float a0 = acc0[r], a1 = acc1[r], a2 = acc2[r], a3 = acc3[r];
        if (bias) {
          a0 += bias[n0 + lm];      a1 += bias[n0 + 16 + lm];
          a2 += bias[n0 + 32 + lm]; a3 += bias[n0 + 48 + lm];
        }
        float s1, c1, s2, c2;
        sincosf((float)s * invf1, &s1, &c1);
        sincosf((float)s * invf2, &s2, &c2);
        u16* op = outB + ((size_t)head * S_LEN + s) * HD;
        op[lm]      = f2bf(a0 * c1 - a2 * s1);
        op[lm + 32] = f2bf(a2 * c1 + a0 * s1);
        op[lm + 16] = f2bf(a1 * c2 - a3 * s2);
        op[lm + 48] = f2bf(a3 * c2 + a1 * s2);
      }
    }
  }
}

// ---------------- fp32 VALU flash attention ----------------
// grid (qtile=32, head=64), block 256. Q/K/V bf16 in (h, s, d) layout, out bf16 (s, h*64+d)
#define SQp 68
__global__ __launch_bounds__(256) void attn_fwd(
    const u16* __restrict__ Qb, const u16* __restrict__ Kb,
    const u16* __restrict__ Vb, u16* __restrict__ attnb) {
  __shared__ __align__(16) float Qs[64 * SQp];
  __shared__ __align__(16) float KS[64 * SQp];  // union: K^T (stride 64) then Sc (stride 68)
  __shared__ __align__(16) float Vs[64 * 64];
  __shared__ float mrow[64], lrow[64], arow[64];
  int t = threadIdx.x;
  int qt = blockIdx.x, h = blockIdx.y;
  int q0 = qt * 64, kvh = h >> 3;
  const u16* Qp = Qb + ((size_t)h * S_LEN + q0) * HD;
  for (int p = 0; p < 2; ++p) {
    int idx = p * 2048 + t * 8;
    int row = idx >> 6, col = idx & 63;
    uint4 r = *(const uint4*)(Qp + (size_t)row * HD + col);
    u32 a[4] = {r.x, r.y, r.z, r.w};
    float* dst = &Qs[row * SQp + col];
    for (int e = 0; e < 4; ++e) {
      dst[2 * e]     = __uint_as_float(a[e] << 16) * 0.125f;
      dst[2 * e + 1] = __uint_as_float(a[e] & 0xffff0000u) * 0.125f;
    }
  }
  if (t < 64) { mrow[t] = -1e30f; lrow[t] = 0.0f; }
  float oacc[4][4] = {};
  int tq = t >> 4, tk = t & 15;
  int nch = qt + 1;
  for (int c = 0; c < nch; ++c) {
    int k0 = c * 64;
    __syncthreads();  // protect LDS from previous iteration readers
    const u16* Kp = Kb + ((size_t)kvh * S_LEN + k0) * HD;
    const u16* Vp = Vb + ((size_t)kvh * S_LEN + k0) * HD;
    for (int p = 0; p < 2; ++p) {
      int idx = p * 2048 + t * 8;
      int row = idx >> 6, col = idx & 63;
      uint4 kr = *(const uint4*)(Kp + (size_t)row * HD + col);
      u32 ka[4] = {kr.x, kr.y, kr.z, kr.w};
      for (int e = 0; e < 4; ++e) {
        KS[(col + 2 * e) * 64 + row]     = __uint_as_float(ka[e] << 16);
        KS[(col + 2 * e + 1) * 64 + row] = __uint_as_float(ka[e] & 0xffff0000u);
      }
      uint4 vr = *(const uint4*)(Vp + (size_t)row * HD + col);
      u32 va[4] = {vr.x, vr.y, vr.z, vr.w};
      float* vdst = &Vs[row * 64 + col];
      for (int e = 0; e < 4; ++e) {
        vdst[2 * e]     = __uint_as_float(va[e] << 16);
        vdst[2 * e + 1] = __uint_as_float(va[e] & 0xffff0000u);
      }
    }
    __syncthreads();
    // S = (Q*scale) K^T
    float sacc[4][4] = {};
    for (int d4 = 0; d4 < 16; ++d4) {
      f4 qv[4], kv[4];
      for (int i = 0; i < 4; ++i) qv[i] = *(const f4*)&Qs[(tq * 4 + i) * SQp + d4 * 4];
      for (int dd = 0; dd < 4; ++dd) kv[dd] = *(const f4*)&KS[(d4 * 4 + dd) * 64 + tk * 4];
      for (int i = 0; i < 4; ++i)
        for (int j = 0; j < 4; ++j)
          sacc[i][j] += qv[i][0] * kv[0][j] + qv[i][1] * kv[1][j] +
                        qv[i][2] * kv[2][j] + qv[i][3] * kv[3][j];
    }
    __syncthreads();  // all K^T reads done before overwriting as Sc
    for (int i = 0; i < 4; ++i) {
      f4 sv = {sacc[i][0], sacc[i][1], sacc[i][2], sacc[i][3]};
      *(f4*)&KS[(tq * 4 + i) * SQp + tk * 4] = sv;
    }
    __syncthreads();
    // online softmax over the 64 new columns
    {
      int row = t >> 2, seg = t & 3;
      bool diag = (c == qt);
      float x[16];
      float* sp = &KS[row * SQp + seg * 16];
      for (int e4 = 0; e4 < 4; ++e4) {
        f4 v = *(const f4*)(sp + e4 * 4);
        x[e4 * 4 + 0] = v[0]; x[e4 * 4 + 1] = v[1];
        x[e4 * 4 + 2] = v[2]; x[e4 * 4 + 3] = v[3];
      }
      int lim = diag ? (row - seg * 16) : 100;
      float mloc = -1e30f;
      for (int e = 0; e < 16; ++e) if (e <= lim) mloc = fmaxf(mloc, x[e]);
      mloc = fmaxf(mloc, __shfl_xor(mloc, 1));
      mloc = fmaxf(mloc, __shfl_xor(mloc, 2));
      float mprev = mrow[row];
      float mnew = fmaxf(mprev, mloc);
      float alpha = __expf(mprev - mnew);
      float sloc = 0.0f;
      for (int e = 0; e < 16; ++e) {
        float p_ = (e <= lim) ? __expf(x[e] - mnew) : 0.0f;
        x[e] = p_; sloc += p_;
      }
      for (int e4 = 0; e4 < 4; ++e4) {
        f4 v = {x[e4 * 4], x[e4 * 4 + 1], x[e4 * 4 + 2], x[e4 * 4 + 3]};
        *(f4*)(sp + e4 * 4) = v;
      }
      sloc += __shfl_xor(sloc, 1);
      sloc += __shfl_xor(sloc, 2);
      if (seg == 0) {
        arow[row] = alpha;
        mrow[row] = mnew;
        lrow[row] = lrow[row] * alpha + sloc;
      }
    }
    __syncthreads();
    // O = O*alpha + P V
    float ai[4];
    for (int i = 0; i < 4; ++i) ai[i] = arow[tq * 4 + i];
    for (int i = 0; i < 4; ++i)
      for (int j = 0; j < 4; ++j) oacc[i][j] *= ai[i];
    for (int k4 = 0; k4 < 16; ++k4) {
      f4 pv[4], vv[4];
      for (int i = 0; i < 4; ++i) pv[i] = *(const f4*)&KS[(tq * 4 + i) * SQp + k4 * 4];
      for (int jj = 0; jj < 4; ++jj) vv[jj] = *(const f4*)&Vs[(k4 * 4 + jj) * 64 + tk * 4];
      for (int i = 0; i < 4; ++i)
        for (int j = 0; j < 4; ++j)
          oacc[i][j] += pv[i][0] * vv[0][j] + pv[i][1] * vv[1][j] +
                        pv[i][2] * vv[2][j] + pv[i][3] * vv[3][j];
    }
  }
  for (int i = 0; i < 4; ++i) {
    int row = tq * 4 + i;
    float linv = 1.0f / lrow[row];
    ushort4 o;
    o.x = f2bf(oacc[i][0] * linv);
    o.y = f2bf(oacc[i][1] * linv);
    o.z = f2bf(oacc[i][2] * linv);
    o.w = f2bf(oacc[i][3] * linv);
    *(ushort4*)(attnb + ((size_t)(q0 + row) * NQD + h * HD + tk * 4)) = o;
  }
}

extern "C" void kernel_launch(void* const* d_in, const int* in_sizes, int n_in,
                              void* d_out, int out_size, void* d_ws, size_t ws_size,
                              hipStream_t stream) {
  (void)in_sizes; (void)n_in; (void)out_size; (void)ws_size;
  const float* hidden = (const float*)d_in[0];
  // d_in[1] = attention_mask (exactly causal; handled analytically)
  const float* q_w    = (const float*)d_in[2];
  const float* q_b    = (const float*)d_in[3];
  const float* kv_a_w = (const float*)d_in[4];
  const float* kv_b_w = (const float*)d_in[5];
  const float* o_w    = (const float*)d_in[6];
  const float* o_b    = (const float*)d_in[7];

  char* ws = (char*)d_ws;
  u16* hb    = (u16*)(ws + 0);           // 2048x2880
  u16* qwb   = (u16*)(ws + 11796480);    // 4096x2880
  u16* kab   = (u16*)(ws + 35389440);    // 384x2880
  u16* kbb   = (u16*)(ws + 37601280);    // 1024x384
  u16* owb   = (u16*)(ws + 38387712);    // 2880x4096
  u16* Qb    = (u16*)(ws + 61980672);    // (64,2048,64) roped
  u16* CKVb  = (u16*)(ws + 78757888);    // 2048x384
  u16* Kb    = (u16*)(ws + 80330752);    // (8,2048,64) roped
  u16* Vb    = (u16*)(ws + 82427904);    // (8,2048,64)
  u16* attnb = (u16*)(ws + 84525056);    // 2048x4096

  conv_f2b<<<(1474560 + 255) / 256, 256, 0, stream>>>(hidden, hb, 1474560);
  conv_f2b<<<(2949120 + 255) / 256, 256, 0, stream>>>(q_w, qwb, 2949120);
  conv_f2b<<<(276480 + 255) / 256, 256, 0, stream>>>(kv_a_w, kab, 276480);
  conv_f2b<<<(98304 + 255) / 256, 256, 0, stream>>>(kv_b_w, kbb, 98304);
  conv_f2b<<<(2949120 + 255) / 256, 256, 0, stream>>>(o_w, owb, 2949120);

  gemm_bt<<<dim3(32, 64), 256, 0, stream>>>(hb, qwb, q_b, S_LEN, NQD, H_DIM, 1, Qb, nullptr);
  gemm_bt<<<dim3(32, 6),  256, 0, stream>>>(hb, kab, nullptr, S_LEN, RANKD, H_DIM, 3, CKVb, nullptr);
  gemm_bt<<<dim3(32, 16), 256, 0, stream>>>(CKVb, kbb, nullptr, S_LEN, 1024, RANKD, 2, Kb, Vb);
  attn_fwd<<<dim3(32, 64), 256, 0, stream>>>(Qb, Kb, Vb, attnb);
  gemm_bt<<<dim3(32, 45), 256, 0, stream>>>(attnb, owb, o_b, S_LEN, H_DIM, NQD, 0, d_out, nullptr);
}

// Round 2
// 895.069 us; speedup vs baseline: 2.3949x; 2.3949x over previous
//
#include <hip/hip_runtime.h>
#include <math.h>

typedef unsigned short u16;
typedef unsigned int u32;
typedef float f4 __attribute__((ext_vector_type(4)));
typedef short bf16x8 __attribute__((ext_vector_type(8)));
typedef float f32x4 __attribute__((ext_vector_type(4)));

#define S_LEN 2048
#define H_DIM 2880
#define NQD 4096
#define RANKD 384
#define HD 64
#define NH 64
#define NKV 8
#define RLN 0.37244970541f  /* ln(150000)/32 */

__device__ __forceinline__ u16 f2bf(float f) {
  u32 u = __float_as_uint(f);
  u += 0x7fffu + ((u >> 16) & 1u);
  return (u16)(u >> 16);
}

// ---------------- fp32 -> bf16 convert ----------------
__global__ void conv_f2b(const float* __restrict__ in, u16* __restrict__ out, int n4) {
  int i = blockIdx.x * blockDim.x + threadIdx.x;
  if (i >= n4) return;
  f4 v = ((const f4*)in)[i];
  ushort4 o;
  o.x = f2bf(v[0]); o.y = f2bf(v[1]); o.z = f2bf(v[2]); o.w = f2bf(v[3]);
  ((ushort4*)out)[i] = o;
}

// ---------------- bf16 MFMA GEMM:  C(MxN) = A(MxK) @ W(NxK)^T (+bias) ----------------
// mode 0: fp32 row-major out0 (+bias)
// mode 1: Q: RoPE + 1/8 scale, write bf16 out0[(head*S + s)*64 + d], head = n0/64
// mode 2: KV: even n-tiles = K half (RoPE -> out0 (kvh,s,d)),
//             odd = V half (plain -> out1 TRANSPOSED (kvh,d,s)), kvh = n0/128
// mode 3: bf16 row-major out0
__global__ __launch_bounds__(256) void gemm_bt(
    const u16* __restrict__ A, const u16* __restrict__ W,
    const float* __restrict__ bias,
    int M, int N, int K, int mode,
    void* __restrict__ out0, void* __restrict__ out1) {
  __shared__ __align__(16) u16 As[64 * 32];
  __shared__ __align__(16) u16 Bs[64 * 32];
  int t = threadIdx.x;
  int m0 = blockIdx.x * 64, n0 = blockIdx.y * 64;
  int w = t >> 6, L = t & 63;
  int srow = t >> 2, scol = (t & 3) * 8;
  int lm = L & 15, quad = L >> 4;
  const u16* Ap = A + (size_t)(m0 + srow) * K + scol;
  const u16* Wp = W + (size_t)(n0 + srow) * K + scol;
  f32x4 acc0 = {0.f, 0.f, 0.f, 0.f}, acc1 = acc0, acc2 = acc0, acc3 = acc0;
  int aoff = (w * 16 + lm) * 32 + quad * 8;
  int boff = lm * 32 + quad * 8;
  int nk = K >> 5;
  uint4 av = *(const uint4*)Ap;
  uint4 wv = *(const uint4*)Wp;
  for (int kt = 0; kt < nk; ++kt) {
    *(uint4*)&As[srow * 32 + scol] = av;
    *(uint4*)&Bs[srow * 32 + scol] = wv;
    __syncthreads();
    if (kt + 1 < nk) {
      Ap += 32; Wp += 32;
      av = *(const uint4*)Ap;
      wv = *(const uint4*)Wp;
    }
    bf16x8 af = *(const bf16x8*)&As[aoff];
    bf16x8 b0 = *(const bf16x8*)&Bs[boff];
    bf16x8 b1 = *(const bf16x8*)&Bs[boff + 16 * 32];
    bf16x8 b2 = *(const bf16x8*)&Bs[boff + 32 * 32];
    bf16x8 b3 = *(const bf16x8*)&Bs[boff + 48 * 32];
    acc0 = __builtin_amdgcn_mfma_f32_16x16x32_bf16(af, b0, acc0, 0, 0, 0);
    acc1 = __builtin_amdgcn_mfma_f32_16x16x32_bf16(af, b1, acc1, 0, 0, 0);
    acc2 = __builtin_amdgcn_mfma_f32_16x16x32_bf16(af, b2, acc2, 0, 0, 0);
    acc3 = __builtin_amdgcn_mfma_f32_16x16x32_bf16(af, b3, acc3, 0, 0, 0);
    __syncthreads();
  }
  int mbase = m0 + w * 16 + quad * 4;
  if (mode == 0) {
    float* outF = (float*)out0;
    for (int r = 0; r < 4; ++r) {
      int row = mbase + r;
      float vals[4] = {acc0[r], acc1[r], acc2[r], acc3[r]};
      for (int nt = 0; nt < 4; ++nt) {
        int col = n0 + nt * 16 + lm;
        float v = vals[nt];
        if (bias) v += bias[col];
        outF[(size_t)row * N + col] = v;
      }
    }
  } else if (mode == 3) {
    u16* outB = (u16*)out0;
    for (int r = 0; r < 4; ++r) {
      int row = mbase + r;
      float vals[4] = {acc0[r], acc1[r], acc2[r], acc3[r]};
      for (int nt = 0; nt < 4; ++nt) {
        int col = n0 + nt * 16 + lm;
        float v = vals[nt];
        if (bias) v += bias[col];
        outB[(size_t)row * N + col] = f2bf(v);
      }
    }
  } else {
    bool isV = (mode == 2) && ((blockIdx.y & 1) == 1);
    int head = (mode == 1) ? (n0 >> 6) : (n0 >> 7);
    if (isV) {
      // write V transposed: out1[(head*64 + d)*2048 + s]
      u16* outB = (u16*)out1;
      for (int r = 0; r < 4; ++r) {
        int s = mbase + r;
        float vals[4] = {acc0[r], acc1[r], acc2[r], acc3[r]};
        for (int nt = 0; nt < 4; ++nt)
          outB[(size_t)(head * 64 + nt * 16 + lm) * S_LEN + s] = f2bf(vals[nt]);
      }
    } else {
      u16* outB = (u16*)out0;
      float qscale = (mode == 1) ? 0.125f : 1.0f;
      float invf1 = __expf(-(float)lm * RLN);
      float invf2 = __expf(-(float)(lm + 16) * RLN);
      for (int r = 0; r < 4; ++r) {
        int s = mbase + r;
        float a0 = acc0[r], a1 = acc1[r], a2 = acc2[r], a3 = acc3[r];
        if (bias) {
          a0 += bias[n0 + lm];      a1 += bias[n0 + 16 + lm];
          a2 += bias[n0 + 32 + lm]; a3 += bias[n0 + 48 + lm];
        }
        float s1, c1, s2, c2;
        sincosf((float)s * invf1, &s1, &c1);
        sincosf((float)s * invf2, &s2, &c2);
        u16* op = outB + ((size_t)head * S_LEN + s) * HD;
        op[lm]      = f2bf((a0 * c1 - a2 * s1) * qscale);
        op[lm + 32] = f2bf((a2 * c1 + a0 * s1) * qscale);
        op[lm + 16] = f2bf((a1 * c2 - a3 * s2) * qscale);
        op[lm + 48] = f2bf((a3 * c2 + a1 * s2) * qscale);
      }
    }
  }
}

// ---------------- MFMA flash attention ----------------
// grid (32 qtiles, 64 heads), block 256 (4 waves). No __syncthreads at all:
// Q/K/V fragments load directly from global (V pre-transposed), P goes through
// a per-wave-private LDS region (C-layout -> A-layout transform).
// Q pre-scaled by 1/8. Output bf16 (s, h*64+d).
__global__ __launch_bounds__(256) void attn_mfma(
    const u16* __restrict__ Qb, const u16* __restrict__ Kb,
    const u16* __restrict__ Vt, u16* __restrict__ attnb) {
  __shared__ __align__(16) u16 Ps[4 * 16 * 68];  // 4 waves x (16 rows x stride 68)
  int t = threadIdx.x;
  int w = t >> 6, L = t & 63;
  int lm = L & 15, quad = L >> 4;
  int qt = blockIdx.x, h = blockIdx.y;
  int q0 = qt * 64, kvh = h >> 3;

  // Q A-fragments (kept in registers for the whole block)
  const u16* Qp = Qb + ((size_t)h * S_LEN + q0 + w * 16 + lm) * HD + quad * 8;
  bf16x8 qf0 = *(const bf16x8*)Qp;
  bf16x8 qf1 = *(const bf16x8*)(Qp + 32);

  f32x4 o0 = {0.f, 0.f, 0.f, 0.f}, o1 = o0, o2 = o0, o3 = o0;
  float m_[4] = {-3.0e38f, -3.0e38f, -3.0e38f, -3.0e38f};
  float l_[4] = {0.f, 0.f, 0.f, 0.f};  // per-lane partial row sums

  const u16* KpBase = Kb + ((size_t)kvh * S_LEN + lm) * HD + quad * 8;
  const u16* VpBase = Vt + ((size_t)(kvh * 64 + lm)) * S_LEN + quad * 8;
  u16* pw = &Ps[w * 16 * 68];

  for (int c = 0; c <= qt; ++c) {
    int k0 = c * 64;
    // ---- S = Q K^T (rows q, cols kv) ----
    const u16* Kp = KpBase + (size_t)k0 * HD;
    f32x4 s0 = {0.f, 0.f, 0.f, 0.f}, s1 = s0, s2 = s0, s3 = s0;
    {
      bf16x8 ka = *(const bf16x8*)(Kp);
      bf16x8 kb = *(const bf16x8*)(Kp + 32);
      s0 = __builtin_amdgcn_mfma_f32_16x16x32_bf16(qf0, ka, s0, 0, 0, 0);
      s0 = __builtin_amdgcn_mfma_f32_16x16x32_bf16(qf1, kb, s0, 0, 0, 0);
      ka = *(const bf16x8*)(Kp + 1024);
      kb = *(const bf16x8*)(Kp + 1024 + 32);
      s1 = __builtin_amdgcn_mfma_f32_16x16x32_bf16(qf0, ka, s1, 0, 0, 0);
      s1 = __builtin_amdgcn_mfma_f32_16x16x32_bf16(qf1, kb, s1, 0, 0, 0);
      ka = *(const bf16x8*)(Kp + 2048);
      kb = *(const bf16x8*)(Kp + 2048 + 32);
      s2 = __builtin_amdgcn_mfma_f32_16x16x32_bf16(qf0, ka, s2, 0, 0, 0);
      s2 = __builtin_amdgcn_mfma_f32_16x16x32_bf16(qf1, kb, s2, 0, 0, 0);
      ka = *(const bf16x8*)(Kp + 3072);
      kb = *(const bf16x8*)(Kp + 3072 + 32);
      s3 = __builtin_amdgcn_mfma_f32_16x16x32_bf16(qf0, ka, s3, 0, 0, 0);
      s3 = __builtin_amdgcn_mfma_f32_16x16x32_bf16(qf1, kb, s3, 0, 0, 0);
    }
    // ---- causal mask on the diagonal chunk ----
    if (c == qt) {
      int rowb = w * 16 + quad * 4;
      for (int r = 0; r < 4; ++r) {
        int row = rowb + r;
        if (lm > row)      s0[r] = -3.0e38f;
        if (lm + 16 > row) s1[r] = -3.0e38f;
        if (lm + 32 > row) s2[r] = -3.0e38f;
        if (lm + 48 > row) s3[r] = -3.0e38f;
      }
    }
    // ---- online softmax (row = quad*4+r, 64 cols across 16 lanes x 4 tiles) ----
    for (int r = 0; r < 4; ++r) {
      float mx = fmaxf(fmaxf(s0[r], s1[r]), fmaxf(s2[r], s3[r]));
      mx = fmaxf(mx, __shfl_xor(mx, 1));
      mx = fmaxf(mx, __shfl_xor(mx, 2));
      mx = fmaxf(mx, __shfl_xor(mx, 4));
      mx = fmaxf(mx, __shfl_xor(mx, 8));
      float mn = fmaxf(m_[r], mx);
      float al = __expf(m_[r] - mn);
      m_[r] = mn;
      float p0 = __expf(s0[r] - mn);
      float p1 = __expf(s1[r] - mn);
      float p2 = __expf(s2[r] - mn);
      float p3 = __expf(s3[r] - mn);
      l_[r] = l_[r] * al + ((p0 + p1) + (p2 + p3));
      o0[r] *= al; o1[r] *= al; o2[r] *= al; o3[r] *= al;
      u16* pp = pw + (quad * 4 + r) * 68 + lm;
      pp[0]  = (u16)(__float_as_uint(p0) >> 16);
      pp[16] = (u16)(__float_as_uint(p1) >> 16);
      pp[32] = (u16)(__float_as_uint(p2) >> 16);
      pp[48] = (u16)(__float_as_uint(p3) >> 16);
    }
    // ---- P: C-layout -> A-layout via private LDS ----
    union { uint2 u[2]; bf16x8 v; } pa, pb;
    const u16* pr = pw + lm * 68 + quad * 8;
    pa.u[0] = *(const uint2*)(pr);
    pa.u[1] = *(const uint2*)(pr + 4);
    pb.u[0] = *(const uint2*)(pr + 32);
    pb.u[1] = *(const uint2*)(pr + 36);
    // ---- O += P V  (V^T fragments direct from global) ----
    const u16* Vp = VpBase + k0;
    bf16x8 va = *(const bf16x8*)(Vp);
    bf16x8 vb = *(const bf16x8*)(Vp + 32);
    o0 = __builtin_amdgcn_mfma_f32_16x16x32_bf16(pa.v, va, o0, 0, 0, 0);
    o0 = __builtin_amdgcn_mfma_f32_16x16x32_bf16(pb.v, vb, o0, 0, 0, 0);
    va = *(const bf16x8*)(Vp + 16 * S_LEN);
    vb = *(const bf16x8*)(Vp + 16 * S_LEN + 32);
    o1 = __builtin_amdgcn_mfma_f32_16x16x32_bf16(pa.v, va, o1, 0, 0, 0);
    o1 = __builtin_amdgcn_mfma_f32_16x16x32_bf16(pb.v, vb, o1, 0, 0, 0);
    va = *(const bf16x8*)(Vp + 32 * S_LEN);
    vb = *(const bf16x8*)(Vp + 32 * S_LEN + 32);
    o2 = __builtin_amdgcn_mfma_f32_16x16x32_bf16(pa.v, va, o2, 0, 0, 0);
    o2 = __builtin_amdgcn_mfma_f32_16x16x32_bf16(pb.v, vb, o2, 0, 0, 0);
    va = *(const bf16x8*)(Vp + 48 * S_LEN);
    vb = *(const bf16x8*)(Vp + 48 * S_LEN + 32);
    o3 = __builtin_amdgcn_mfma_f32_16x16x32_bf16(pa.v, va, o3, 0, 0, 0);
    o3 = __builtin_amdgcn_mfma_f32_16x16x32_bf16(pb.v, vb, o3, 0, 0, 0);
  }
  // ---- finalize: reduce l across the 16 lanes of the quad group, write O ----
  for (int r = 0; r < 4; ++r) {
    float l = l_[r];
    l += __shfl_xor(l, 1);
    l += __shfl_xor(l, 2);
    l += __shfl_xor(l, 4);
    l += __shfl_xor(l, 8);
    float linv = 1.0f / l;
    int row = q0 + w * 16 + quad * 4 + r;
    u16* op = attnb + (size_t)row * NQD + h * HD + lm;
    op[0]  = f2bf(o0[r] * linv);
    op[16] = f2bf(o1[r] * linv);
    op[32] = f2bf(o2[r] * linv);
    op[48] = f2bf(o3[r] * linv);
  }
}

extern "C" void kernel_launch(void* const* d_in, const int* in_sizes, int n_in,
                              void* d_out, int out_size, void* d_ws, size_t ws_size,
                              hipStream_t stream) {
  (void)in_sizes; (void)n_in; (void)out_size; (void)ws_size;
  const float* hidden = (const float*)d_in[0];
  // d_in[1] = attention_mask (exactly causal; handled analytically)
  const float* q_w    = (const float*)d_in[2];
  const float* q_b    = (const float*)d_in[3];
  const float* kv_a_w = (const float*)d_in[4];
  const float* kv_b_w = (const float*)d_in[5];
  const float* o_w    = (const float*)d_in[6];
  const float* o_b    = (const float*)d_in[7];

  char* ws = (char*)d_ws;
  u16* hb    = (u16*)(ws + 0);           // 2048x2880
  u16* qwb   = (u16*)(ws + 11796480);    // 4096x2880
  u16* kab   = (u16*)(ws + 35389440);    // 384x2880
  u16* kbb   = (u16*)(ws + 37601280);    // 1024x384
  u16* owb   = (u16*)(ws + 38387712);    // 2880x4096
  u16* Qb    = (u16*)(ws + 61980672);    // (64,2048,64) roped, pre-scaled 1/8
  u16* CKVb  = (u16*)(ws + 78757888);    // 2048x384
  u16* Kb    = (u16*)(ws + 80330752);    // (8,2048,64) roped
  u16* Vtb   = (u16*)(ws + 82427904);    // (8,64,2048) V transposed
  u16* attnb = (u16*)(ws + 84525056);    // 2048x4096

  conv_f2b<<<(1474560 + 255) / 256, 256, 0, stream>>>(hidden, hb, 1474560);
  conv_f2b<<<(2949120 + 255) / 256, 256, 0, stream>>>(q_w, qwb, 2949120);
  conv_f2b<<<(276480 + 255) / 256, 256, 0, stream>>>(kv_a_w, kab, 276480);
  conv_f2b<<<(98304 + 255) / 256, 256, 0, stream>>>(kv_b_w, kbb, 98304);
  conv_f2b<<<(2949120 + 255) / 256, 256, 0, stream>>>(o_w, owb, 2949120);

  gemm_bt<<<dim3(32, 64), 256, 0, stream>>>(hb, qwb, q_b, S_LEN, NQD, H_DIM, 1, Qb, nullptr);
  gemm_bt<<<dim3(32, 6),  256, 0, stream>>>(hb, kab, nullptr, S_LEN, RANKD, H_DIM, 3, CKVb, nullptr);
  gemm_bt<<<dim3(32, 16), 256, 0, stream>>>(CKVb, kbb, nullptr, S_LEN, 1024, RANKD, 2, Kb, Vtb);
  attn_mfma<<<dim3(32, 64), 256, 0, stream>>>(Qb, Kb, Vtb, attnb);
  gemm_bt<<<dim3(32, 45), 256, 0, stream>>>(attnb, owb, o_b, S_LEN, H_DIM, NQD, 0, d_out, nullptr);
}

// Round 3
// 624.111 us; speedup vs baseline: 3.4346x; 1.4342x over previous
//
#include <hip/hip_runtime.h>
#include <math.h>

typedef unsigned short u16;
typedef unsigned int u32;
typedef float f4 __attribute__((ext_vector_type(4)));
typedef short bf16x8 __attribute__((ext_vector_type(8)));
typedef float f32x4 __attribute__((ext_vector_type(4)));

#define S_LEN 2048
#define H_DIM 2880
#define NQD 4096
#define RANKD 384
#define HD 64
#define NH 64
#define NKV 8
#define RLN 0.37244970541f  /* ln(150000)/32 */

__device__ __forceinline__ u16 f2bf(float f) {
  u32 u = __float_as_uint(f);
  u += 0x7fffu + ((u >> 16) & 1u);
  return (u16)(u >> 16);
}

#define GLOAD_LDS(g, l) __builtin_amdgcn_global_load_lds( \
    (__attribute__((address_space(1))) void*)(g),          \
    (__attribute__((address_space(3))) void*)(l), 16, 0, 0)

// ---------------- fp32 -> bf16 convert ----------------
__global__ void conv_f2b(const float* __restrict__ in, u16* __restrict__ out, int n4) {
  int i = blockIdx.x * blockDim.x + threadIdx.x;
  if (i >= n4) return;
  f4 v = ((const f4*)in)[i];
  ushort4 o;
  o.x = f2bf(v[0]); o.y = f2bf(v[1]); o.z = f2bf(v[2]); o.w = f2bf(v[3]);
  ((ushort4*)out)[i] = o;
}

// ---------------- 128x128 MFMA GEMM (m97 structure):  C = A(2048xK) @ W(NxK)^T ----------------
// 4 waves in 2x2; each wave 64x64 via 4x4 MFMA tiles. global_load_lds width-16 staging.
// mode 0: fp32 out [2048 x Nreal] + bias, guard col < Nreal (W rows clamped when staging)
// mode 1: Q-proj: RoPE + 1/8 scale, bf16 out0[(head*S + s)*64 + d], head = col/64
__global__ __launch_bounds__(256) void gemm128(
    const u16* __restrict__ A, const u16* __restrict__ W,
    const float* __restrict__ bias, int K, int Nreal, int mode,
    void* __restrict__ out0) {
  __shared__ __align__(16) u16 As[128 * 32];
  __shared__ __align__(16) u16 Bs[128 * 32];
  int t = threadIdx.x, w = t >> 6, L = t & 63;
  int lm = L & 15, quad = L >> 4;
  int m0 = blockIdx.x * 128, n0 = blockIdx.y * 128;
  int wm = w >> 1, wn = w & 1;
  int srow = L >> 2, scol8 = (L & 3) * 8;
  const u16* Ag0 = A + (size_t)(m0 + (w * 2) * 16 + srow) * K + scol8;
  const u16* Ag1 = Ag0 + (size_t)16 * K;
  int wr0 = n0 + (w * 2) * 16 + srow;      if (wr0 > Nreal - 1) wr0 = Nreal - 1;
  int wr1 = n0 + (w * 2) * 16 + 16 + srow; if (wr1 > Nreal - 1) wr1 = Nreal - 1;
  const u16* Wg0 = W + (size_t)wr0 * K + scol8;
  const u16* Wg1 = W + (size_t)wr1 * K + scol8;
  u16* lA0 = &As[(w * 2) * 512];
  u16* lA1 = &As[(w * 2 + 1) * 512];
  u16* lB0 = &Bs[(w * 2) * 512];
  u16* lB1 = &Bs[(w * 2 + 1) * 512];
  f32x4 acc[4][4] = {};
  int nk = K >> 5;
  for (int kt = 0; kt < nk; ++kt) {
    GLOAD_LDS(Ag0, lA0);
    GLOAD_LDS(Ag1, lA1);
    GLOAD_LDS(Wg0, lB0);
    GLOAD_LDS(Wg1, lB1);
    Ag0 += 32; Ag1 += 32; Wg0 += 32; Wg1 += 32;
    __syncthreads();
    bf16x8 af[4], bf[4];
#pragma unroll
    for (int i = 0; i < 4; ++i) af[i] = *(const bf16x8*)&As[(wm * 64 + i * 16 + lm) * 32 + quad * 8];
#pragma unroll
    for (int j = 0; j < 4; ++j) bf[j] = *(const bf16x8*)&Bs[(wn * 64 + j * 16 + lm) * 32 + quad * 8];
#pragma unroll
    for (int i = 0; i < 4; ++i)
#pragma unroll
      for (int j = 0; j < 4; ++j)
        acc[i][j] = __builtin_amdgcn_mfma_f32_16x16x32_bf16(af[i], bf[j], acc[i][j], 0, 0, 0);
    __syncthreads();
  }
  if (mode == 0) {
    float* outF = (float*)out0;
#pragma unroll
    for (int i = 0; i < 4; ++i) {
#pragma unroll
      for (int r = 0; r < 4; ++r) {
        int row = m0 + wm * 64 + i * 16 + quad * 4 + r;
#pragma unroll
        for (int j = 0; j < 4; ++j) {
          int col = n0 + wn * 64 + j * 16 + lm;
          if (col < Nreal)
            outF[(size_t)row * Nreal + col] = acc[i][j][r] + bias[col];
        }
      }
    }
  } else {
    u16* outB = (u16*)out0;
    int head = (n0 + wn * 64) >> 6;
    float b0v = bias[head * 64 + lm];
    float b1v = bias[head * 64 + 16 + lm];
    float b2v = bias[head * 64 + 32 + lm];
    float b3v = bias[head * 64 + 48 + lm];
    float invf1 = __expf(-(float)lm * RLN);
    float invf2 = __expf(-(float)(lm + 16) * RLN);
#pragma unroll
    for (int i = 0; i < 4; ++i) {
      int sq = m0 + wm * 64 + i * 16 + quad * 4;
#pragma unroll
      for (int r = 0; r < 4; ++r) {
        float a0 = acc[i][0][r] + b0v, a1 = acc[i][1][r] + b1v;
        float a2 = acc[i][2][r] + b2v, a3 = acc[i][3][r] + b3v;
        float s1, c1, s2, c2;
        sincosf((float)(sq + r) * invf1, &s1, &c1);
        sincosf((float)(sq + r) * invf2, &s2, &c2);
        u16* op = outB + ((size_t)head * S_LEN + sq + r) * HD;
        op[lm]      = f2bf((a0 * c1 - a2 * s1) * 0.125f);
        op[lm + 32] = f2bf((a2 * c1 + a0 * s1) * 0.125f);
        op[lm + 16] = f2bf((a1 * c2 - a3 * s2) * 0.125f);
        op[lm + 48] = f2bf((a3 * c2 + a1 * s2) * 0.125f);
      }
    }
  }
}

// ---------------- 64x64 MFMA GEMM (kept for the two small GEMMs) ----------------
// mode 2: KV: even n-tiles = K half (RoPE -> out0 (kvh,s,d)),
//             odd = V half (plain -> out1 TRANSPOSED (kvh,d,s)), kvh = n0/128
// mode 3: bf16 row-major out0
__global__ __launch_bounds__(256) void gemm_bt(
    const u16* __restrict__ A, const u16* __restrict__ W,
    const float* __restrict__ bias,
    int M, int N, int K, int mode,
    void* __restrict__ out0, void* __restrict__ out1) {
  __shared__ __align__(16) u16 As[64 * 32];
  __shared__ __align__(16) u16 Bs[64 * 32];
  int t = threadIdx.x;
  int m0 = blockIdx.x * 64, n0 = blockIdx.y * 64;
  int w = t >> 6, L = t & 63;
  int srow = t >> 2, scol = (t & 3) * 8;
  int lm = L & 15, quad = L >> 4;
  const u16* Ap = A + (size_t)(m0 + srow) * K + scol;
  const u16* Wp = W + (size_t)(n0 + srow) * K + scol;
  f32x4 acc0 = {0.f, 0.f, 0.f, 0.f}, acc1 = acc0, acc2 = acc0, acc3 = acc0;
  int aoff = (w * 16 + lm) * 32 + quad * 8;
  int boff = lm * 32 + quad * 8;
  int nk = K >> 5;
  uint4 av = *(const uint4*)Ap;
  uint4 wv = *(const uint4*)Wp;
  for (int kt = 0; kt < nk; ++kt) {
    *(uint4*)&As[srow * 32 + scol] = av;
    *(uint4*)&Bs[srow * 32 + scol] = wv;
    __syncthreads();
    if (kt + 1 < nk) {
      Ap += 32; Wp += 32;
      av = *(const uint4*)Ap;
      wv = *(const uint4*)Wp;
    }
    bf16x8 af = *(const bf16x8*)&As[aoff];
    bf16x8 b0 = *(const bf16x8*)&Bs[boff];
    bf16x8 b1 = *(const bf16x8*)&Bs[boff + 16 * 32];
    bf16x8 b2 = *(const bf16x8*)&Bs[boff + 32 * 32];
    bf16x8 b3 = *(const bf16x8*)&Bs[boff + 48 * 32];
    acc0 = __builtin_amdgcn_mfma_f32_16x16x32_bf16(af, b0, acc0, 0, 0, 0);
    acc1 = __builtin_amdgcn_mfma_f32_16x16x32_bf16(af, b1, acc1, 0, 0, 0);
    acc2 = __builtin_amdgcn_mfma_f32_16x16x32_bf16(af, b2, acc2, 0, 0, 0);
    acc3 = __builtin_amdgcn_mfma_f32_16x16x32_bf16(af, b3, acc3, 0, 0, 0);
    __syncthreads();
  }
  int mbase = m0 + w * 16 + quad * 4;
  if (mode == 3) {
    u16* outB = (u16*)out0;
    for (int r = 0; r < 4; ++r) {
      int row = mbase + r;
      float vals[4] = {acc0[r], acc1[r], acc2[r], acc3[r]};
      for (int nt = 0; nt < 4; ++nt) {
        int col = n0 + nt * 16 + lm;
        outB[(size_t)row * N + col] = f2bf(vals[nt]);
      }
    }
  } else {
    bool isV = ((blockIdx.y & 1) == 1);
    int head = (n0 >> 7);
    if (isV) {
      // write V transposed: out1[(head*64 + d)*2048 + s]
      u16* outB = (u16*)out1;
      for (int r = 0; r < 4; ++r) {
        int s = mbase + r;
        float vals[4] = {acc0[r], acc1[r], acc2[r], acc3[r]};
        for (int nt = 0; nt < 4; ++nt)
          outB[(size_t)(head * 64 + nt * 16 + lm) * S_LEN + s] = f2bf(vals[nt]);
      }
    } else {
      u16* outB = (u16*)out0;
      float invf1 = __expf(-(float)lm * RLN);
      float invf2 = __expf(-(float)(lm + 16) * RLN);
      for (int r = 0; r < 4; ++r) {
        int s = mbase + r;
        float a0 = acc0[r], a1 = acc1[r], a2 = acc2[r], a3 = acc3[r];
        float s1, c1, s2, c2;
        sincosf((float)s * invf1, &s1, &c1);
        sincosf((float)s * invf2, &s2, &c2);
        u16* op = outB + ((size_t)head * S_LEN + s) * HD;
        op[lm]      = f2bf(a0 * c1 - a2 * s1);
        op[lm + 32] = f2bf(a2 * c1 + a0 * s1);
        op[lm + 16] = f2bf(a1 * c2 - a3 * s2);
        op[lm + 48] = f2bf(a3 * c2 + a1 * s2);
      }
    }
  }
}

// ---------------- MFMA flash attention, load-balanced ----------------
// grid (16, 64): block bx handles q-tiles {bx, 31-bx} -> uniform 33 chunks/wave.
// 4 waves/block, each wave 16 q-rows, no __syncthreads (per-wave-private LDS for P).
// Q pre-scaled by 1/8. V pre-transposed (kvh,d,s). Output bf16 (s, h*64+d).
__global__ __launch_bounds__(256, 4) void attn_mfma2(
    const u16* __restrict__ Qb, const u16* __restrict__ Kb,
    const u16* __restrict__ Vt, u16* __restrict__ attnb) {
  __shared__ __align__(16) u16 Ps[4 * 16 * 68];
  int t = threadIdx.x;
  int w = t >> 6, L = t & 63;
  int lm = L & 15, quad = L >> 4;
  int bx = blockIdx.x, h = blockIdx.y, kvh = h >> 3;
  u16* pw = &Ps[w * 16 * 68];
  const u16* KpBase = Kb + ((size_t)kvh * S_LEN + lm) * HD + quad * 8;
  const u16* VpBase = Vt + ((size_t)(kvh * 64 + lm)) * S_LEN + quad * 8;

  for (int ph = 0; ph < 2; ++ph) {
    int qt = ph ? (31 - bx) : bx;
    int q0 = qt * 64;
    const u16* Qp = Qb + ((size_t)h * S_LEN + q0 + w * 16 + lm) * HD + quad * 8;
    bf16x8 qf0 = *(const bf16x8*)Qp;
    bf16x8 qf1 = *(const bf16x8*)(Qp + 32);
    f32x4 oA[4] = {};
    float m_[4] = {-3.0e38f, -3.0e38f, -3.0e38f, -3.0e38f};
    float l_[4] = {0.f, 0.f, 0.f, 0.f};

    for (int c = 0; c <= qt; ++c) {
      int k0 = c * 64;
      const u16* Kp = KpBase + (size_t)k0 * HD;
      // ---- K fragment loads ----
      bf16x8 kfa[4], kfb[4];
#pragma unroll
      for (int j = 0; j < 4; ++j) {
        kfa[j] = *(const bf16x8*)(Kp + j * 1024);
        kfb[j] = *(const bf16x8*)(Kp + j * 1024 + 32);
      }
      // ---- S = Q K^T ----
      f32x4 sA[4] = {};
#pragma unroll
      for (int j = 0; j < 4; ++j) {
        sA[j] = __builtin_amdgcn_mfma_f32_16x16x32_bf16(qf0, kfa[j], sA[j], 0, 0, 0);
        sA[j] = __builtin_amdgcn_mfma_f32_16x16x32_bf16(qf1, kfb[j], sA[j], 0, 0, 0);
      }
      // ---- V fragment loads (issued early; consumed after softmax) ----
      const u16* Vp = VpBase + k0;
      bf16x8 vfa[4], vfb[4];
#pragma unroll
      for (int j = 0; j < 4; ++j) {
        vfa[j] = *(const bf16x8*)(Vp + j * 16 * S_LEN);
        vfb[j] = *(const bf16x8*)(Vp + j * 16 * S_LEN + 32);
      }
      // ---- causal mask on the diagonal chunk ----
      if (c == qt) {
        int rowb = w * 16 + quad * 4;
#pragma unroll
        for (int r = 0; r < 4; ++r) {
          int row = rowb + r;
          if (lm > row)      sA[0][r] = -3.0e38f;
          if (lm + 16 > row) sA[1][r] = -3.0e38f;
          if (lm + 32 > row) sA[2][r] = -3.0e38f;
          if (lm + 48 > row) sA[3][r] = -3.0e38f;
        }
      }
      // ---- online softmax ----
#pragma unroll
      for (int r = 0; r < 4; ++r) {
        float mx = fmaxf(fmaxf(sA[0][r], sA[1][r]), fmaxf(sA[2][r], sA[3][r]));
        mx = fmaxf(mx, __shfl_xor(mx, 1));
        mx = fmaxf(mx, __shfl_xor(mx, 2));
        mx = fmaxf(mx, __shfl_xor(mx, 4));
        mx = fmaxf(mx, __shfl_xor(mx, 8));
        float mn = fmaxf(m_[r], mx);
        float al = __expf(m_[r] - mn);
        m_[r] = mn;
        float p0 = __expf(sA[0][r] - mn);
        float p1 = __expf(sA[1][r] - mn);
        float p2 = __expf(sA[2][r] - mn);
        float p3 = __expf(sA[3][r] - mn);
        l_[r] = l_[r] * al + ((p0 + p1) + (p2 + p3));
        oA[0][r] *= al; oA[1][r] *= al; oA[2][r] *= al; oA[3][r] *= al;
        u16* pp = pw + (quad * 4 + r) * 68 + lm;
        pp[0]  = (u16)(__float_as_uint(p0) >> 16);
        pp[16] = (u16)(__float_as_uint(p1) >> 16);
        pp[32] = (u16)(__float_as_uint(p2) >> 16);
        pp[48] = (u16)(__float_as_uint(p3) >> 16);
      }
      // ---- P: C-layout -> A-layout via private LDS ----
      union { uint2 u[2]; bf16x8 v; } pa, pb;
      const u16* pr = pw + lm * 68 + quad * 8;
      pa.u[0] = *(const uint2*)(pr);
      pa.u[1] = *(const uint2*)(pr + 4);
      pb.u[0] = *(const uint2*)(pr + 32);
      pb.u[1] = *(const uint2*)(pr + 36);
      // ---- O += P V ----
#pragma unroll
      for (int j = 0; j < 4; ++j) {
        oA[j] = __builtin_amdgcn_mfma_f32_16x16x32_bf16(pa.v, vfa[j], oA[j], 0, 0, 0);
        oA[j] = __builtin_amdgcn_mfma_f32_16x16x32_bf16(pb.v, vfb[j], oA[j], 0, 0, 0);
      }
    }
    // ---- finalize ----
#pragma unroll
    for (int r = 0; r < 4; ++r) {
      float l = l_[r];
      l += __shfl_xor(l, 1);
      l += __shfl_xor(l, 2);
      l += __shfl_xor(l, 4);
      l += __shfl_xor(l, 8);
      float linv = 1.0f / l;
      int row = q0 + w * 16 + quad * 4 + r;
      u16* op = attnb + (size_t)row * NQD + h * HD + lm;
      op[0]  = f2bf(oA[0][r] * linv);
      op[16] = f2bf(oA[1][r] * linv);
      op[32] = f2bf(oA[2][r] * linv);
      op[48] = f2bf(oA[3][r] * linv);
    }
  }
}

extern "C" void kernel_launch(void* const* d_in, const int* in_sizes, int n_in,
                              void* d_out, int out_size, void* d_ws, size_t ws_size,
                              hipStream_t stream) {
  (void)in_sizes; (void)n_in; (void)out_size; (void)ws_size;
  const float* hidden = (const float*)d_in[0];
  // d_in[1] = attention_mask (exactly causal; handled analytically)
  const float* q_w    = (const float*)d_in[2];
  const float* q_b    = (const float*)d_in[3];
  const float* kv_a_w = (const float*)d_in[4];
  const float* kv_b_w = (const float*)d_in[5];
  const float* o_w    = (const float*)d_in[6];
  const float* o_b    = (const float*)d_in[7];

  char* ws = (char*)d_ws;
  u16* hb    = (u16*)(ws + 0);           // 2048x2880
  u16* qwb   = (u16*)(ws + 11796480);    // 4096x2880
  u16* kab   = (u16*)(ws + 35389440);    // 384x2880
  u16* kbb   = (u16*)(ws + 37601280);    // 1024x384
  u16* owb   = (u16*)(ws + 38387712);    // 2880x4096
  u16* Qb    = (u16*)(ws + 61980672);    // (64,2048,64) roped, pre-scaled 1/8
  u16* CKVb  = (u16*)(ws + 78757888);    // 2048x384
  u16* Kb    = (u16*)(ws + 80330752);    // (8,2048,64) roped
  u16* Vtb   = (u16*)(ws + 82427904);    // (8,64,2048) V transposed
  u16* attnb = (u16*)(ws + 84525056);    // 2048x4096

  conv_f2b<<<(1474560 + 255) / 256, 256, 0, stream>>>(hidden, hb, 1474560);
  conv_f2b<<<(2949120 + 255) / 256, 256, 0, stream>>>(q_w, qwb, 2949120);
  conv_f2b<<<(276480 + 255) / 256, 256, 0, stream>>>(kv_a_w, kab, 276480);
  conv_f2b<<<(98304 + 255) / 256, 256, 0, stream>>>(kv_b_w, kbb, 98304);
  conv_f2b<<<(2949120 + 255) / 256, 256, 0, stream>>>(o_w, owb, 2949120);

  gemm128<<<dim3(16, 32), 256, 0, stream>>>(hb, qwb, q_b, H_DIM, NQD, 1, Qb);
  gemm_bt<<<dim3(32, 6),  256, 0, stream>>>(hb, kab, nullptr, S_LEN, RANKD, H_DIM, 3, CKVb, nullptr);
  gemm_bt<<<dim3(32, 16), 256, 0, stream>>>(CKVb, kbb, nullptr, S_LEN, 1024, RANKD, 2, Kb, Vtb);
  attn_mfma2<<<dim3(16, 64), 256, 0, stream>>>(Qb, Kb, Vtb, attnb);
  gemm128<<<dim3(16, 23), 256, 0, stream>>>(attnb, owb, o_b, NQD, H_DIM, 0, d_out);
}

// Round 5
// 460.504 us; speedup vs baseline: 4.6549x; 1.3553x over previous
//
#include <hip/hip_runtime.h>
#include <math.h>

typedef unsigned short u16;
typedef unsigned int u32;
typedef float f4 __attribute__((ext_vector_type(4)));
typedef short bf16x8 __attribute__((ext_vector_type(8)));
typedef float f32x4 __attribute__((ext_vector_type(4)));

#define S_LEN 2048
#define H_DIM 2880
#define NQD 4096
#define RANKD 384
#define HD 64
#define NH 64
#define NKV 8
#define RLN 0.37244970541f  /* ln(150000)/32 */

__device__ __forceinline__ u16 f2bf(float f) {
  u32 u = __float_as_uint(f);
  u += 0x7fffu + ((u >> 16) & 1u);
  return (u16)(u >> 16);
}

#define GLOAD_LDS(g, l) __builtin_amdgcn_global_load_lds( \
    (__attribute__((address_space(1))) void*)(g),          \
    (__attribute__((address_space(3))) void*)(l), 16, 0, 0)

// Fragment-linear K layout (A-operand of K@Q^T):
// u16 offset for element (kvh, s, d)
__device__ __forceinline__ size_t koff_s(int s) {
  return (size_t)((s >> 6) * 4096 + ((s >> 4) & 3) * 1024 + (s & 15) * 8);
}
__device__ __forceinline__ int koff_d(int d) {
  return (d >> 5) * 512 + ((d >> 3) & 3) * 128 + (d & 7);
}
// Fragment-linear V^T layout (B-operand of P@V):
__device__ __forceinline__ size_t voff_s(int s) {
  return (size_t)((s >> 6) * 4096 + ((s >> 5) & 1) * 512 + ((s >> 3) & 3) * 128 + (s & 7));
}
__device__ __forceinline__ int voff_d(int d) {
  return ((d >> 4) & 3) * 1024 + (d & 15) * 8;
}

// ---------------- fp32 -> bf16 convert ----------------
__global__ void conv_f2b(const float* __restrict__ in, u16* __restrict__ out, int n4) {
  int i = blockIdx.x * blockDim.x + threadIdx.x;
  if (i >= n4) return;
  f4 v = ((const f4*)in)[i];
  ushort4 o;
  o.x = f2bf(v[0]); o.y = f2bf(v[1]); o.z = f2bf(v[2]); o.w = f2bf(v[3]);
  ((ushort4*)out)[i] = o;
}

// ---------------- 128x128 MFMA GEMM: Q-projection ----------------
// RoPE + 1/8 scale, bf16 out0[(head*S + s)*64 + d], head = col/64
__global__ __launch_bounds__(256) void gemm128(
    const u16* __restrict__ A, const u16* __restrict__ W,
    const float* __restrict__ bias, int K,
    u16* __restrict__ out0) {
  __shared__ __align__(16) u16 As[128 * 32];
  __shared__ __align__(16) u16 Bs[128 * 32];
  int t = threadIdx.x, w = t >> 6, L = t & 63;
  int lm = L & 15, quad = L >> 4;
  int m0 = blockIdx.x * 128, n0 = blockIdx.y * 128;
  int wm = w >> 1, wn = w & 1;
  int srow = L >> 2, scol8 = (L & 3) * 8;
  const u16* Ag0 = A + (size_t)(m0 + (w * 2) * 16 + srow) * K + scol8;
  const u16* Ag1 = Ag0 + (size_t)16 * K;
  const u16* Wg0 = W + (size_t)(n0 + (w * 2) * 16 + srow) * K + scol8;
  const u16* Wg1 = Wg0 + (size_t)16 * K;
  u16* lA0 = &As[(w * 2) * 512];
  u16* lA1 = &As[(w * 2 + 1) * 512];
  u16* lB0 = &Bs[(w * 2) * 512];
  u16* lB1 = &Bs[(w * 2 + 1) * 512];
  f32x4 acc[4][4] = {};
  int nk = K >> 5;
  for (int kt = 0; kt < nk; ++kt) {
    GLOAD_LDS(Ag0, lA0);
    GLOAD_LDS(Ag1, lA1);
    GLOAD_LDS(Wg0, lB0);
    GLOAD_LDS(Wg1, lB1);
    Ag0 += 32; Ag1 += 32; Wg0 += 32; Wg1 += 32;
    __syncthreads();
    bf16x8 af[4], bf[4];
#pragma unroll
    for (int i = 0; i < 4; ++i) af[i] = *(const bf16x8*)&As[(wm * 64 + i * 16 + lm) * 32 + quad * 8];
#pragma unroll
    for (int j = 0; j < 4; ++j) bf[j] = *(const bf16x8*)&Bs[(wn * 64 + j * 16 + lm) * 32 + quad * 8];
#pragma unroll
    for (int i = 0; i < 4; ++i)
#pragma unroll
      for (int j = 0; j < 4; ++j)
        acc[i][j] = __builtin_amdgcn_mfma_f32_16x16x32_bf16(af[i], bf[j], acc[i][j], 0, 0, 0);
    __syncthreads();
  }
  int head = (n0 + wn * 64) >> 6;
  float b0v = bias[head * 64 + lm];
  float b1v = bias[head * 64 + 16 + lm];
  float b2v = bias[head * 64 + 32 + lm];
  float b3v = bias[head * 64 + 48 + lm];
  float invf1 = __expf(-(float)lm * RLN);
  float invf2 = __expf(-(float)(lm + 16) * RLN);
#pragma unroll
  for (int i = 0; i < 4; ++i) {
    int sq = m0 + wm * 64 + i * 16 + quad * 4;
#pragma unroll
    for (int r = 0; r < 4; ++r) {
      float a0 = acc[i][0][r] + b0v, a1 = acc[i][1][r] + b1v;
      float a2 = acc[i][2][r] + b2v, a3 = acc[i][3][r] + b3v;
      float s1, c1, s2, c2;
      sincosf((float)(sq + r) * invf1, &s1, &c1);
      sincosf((float)(sq + r) * invf2, &s2, &c2);
      u16* op = out0 + ((size_t)head * S_LEN + sq + r) * HD;
      op[lm]      = f2bf((a0 * c1 - a2 * s1) * 0.125f);
      op[lm + 32] = f2bf((a2 * c1 + a0 * s1) * 0.125f);
      op[lm + 16] = f2bf((a1 * c2 - a3 * s2) * 0.125f);
      op[lm + 48] = f2bf((a3 * c2 + a1 * s2) * 0.125f);
    }
  }
}

// ---------------- 64x128 MFMA GEMM: O-projection (fp32 out + bias) ----------------
__global__ __launch_bounds__(256) void gemm64(
    const u16* __restrict__ A, const u16* __restrict__ W,
    const float* __restrict__ bias, int K, int Nreal,
    float* __restrict__ out) {
  __shared__ __align__(16) u16 As[64 * 32];
  __shared__ __align__(16) u16 Bs[128 * 32];
  int t = threadIdx.x, w = t >> 6, L = t & 63;
  int lm = L & 15, quad = L >> 4;
  int m0 = blockIdx.x * 64, n0 = blockIdx.y * 128;
  int wm = w >> 1, wn = w & 1;
  int srow = L >> 2, scol8 = (L & 3) * 8;
  const u16* Ag = A + (size_t)(m0 + w * 16 + srow) * K + scol8;
  int wr0 = n0 + w * 16 + srow;      if (wr0 > Nreal - 1) wr0 = Nreal - 1;
  int wr1 = n0 + 64 + w * 16 + srow; if (wr1 > Nreal - 1) wr1 = Nreal - 1;
  const u16* Wg0 = W + (size_t)wr0 * K + scol8;
  const u16* Wg1 = W + (size_t)wr1 * K + scol8;
  u16* lA  = &As[w * 512];
  u16* lB0 = &Bs[w * 512];
  u16* lB1 = &Bs[2048 + w * 512];
  f32x4 acc[2][4] = {};
  int nk = K >> 5;
  for (int kt = 0; kt < nk; ++kt) {
    GLOAD_LDS(Ag, lA);
    GLOAD_LDS(Wg0, lB0);
    GLOAD_LDS(Wg1, lB1);
    Ag += 32; Wg0 += 32; Wg1 += 32;
    __syncthreads();
    bf16x8 af[2], bf[4];
#pragma unroll
    for (int i = 0; i < 2; ++i) af[i] = *(const bf16x8*)&As[(wm * 32 + i * 16 + lm) * 32 + quad * 8];
#pragma unroll
    for (int j = 0; j < 4; ++j) bf[j] = *(const bf16x8*)&Bs[(wn * 64 + j * 16 + lm) * 32 + quad * 8];
#pragma unroll
    for (int i = 0; i < 2; ++i)
#pragma unroll
      for (int j = 0; j < 4; ++j)
        acc[i][j] = __builtin_amdgcn_mfma_f32_16x16x32_bf16(af[i], bf[j], acc[i][j], 0, 0, 0);
    __syncthreads();
  }
#pragma unroll
  for (int i = 0; i < 2; ++i) {
#pragma unroll
    for (int r = 0; r < 4; ++r) {
      int row = m0 + wm * 32 + i * 16 + quad * 4 + r;
#pragma unroll
      for (int j = 0; j < 4; ++j) {
        int col = n0 + wn * 64 + j * 16 + lm;
        if (col < Nreal)
          out[(size_t)row * Nreal + col] = acc[i][j][r] + bias[col];
      }
    }
  }
}

// ---------------- 64x64 MFMA GEMM for the two small KV GEMMs ----------------
// mode 2: KV: even n-tiles = K half (RoPE -> fragment-linear K layout),
//             odd = V half (-> fragment-linear V^T layout), kvh = n0/128
// mode 3: bf16 row-major out0
__global__ __launch_bounds__(256) void gemm_bt(
    const u16* __restrict__ A, const u16* __restrict__ W,
    int M, int N, int K, int mode,
    u16* __restrict__ out0, u16* __restrict__ out1) {
  __shared__ __align__(16) u16 As[64 * 32];
  __shared__ __align__(16) u16 Bs[64 * 32];
  int t = threadIdx.x;
  int m0 = blockIdx.x * 64, n0 = blockIdx.y * 64;
  int w = t >> 6, L = t & 63;
  int srow = t >> 2, scol = (t & 3) * 8;
  int lm = L & 15, quad = L >> 4;
  const u16* Ap = A + (size_t)(m0 + srow) * K + scol;
  const u16* Wp = W + (size_t)(n0 + srow) * K + scol;
  f32x4 acc0 = {0.f, 0.f, 0.f, 0.f}, acc1 = acc0, acc2 = acc0, acc3 = acc0;
  int aoff = (w * 16 + lm) * 32 + quad * 8;
  int boff = lm * 32 + quad * 8;
  int nk = K >> 5;
  uint4 av = *(const uint4*)Ap;
  uint4 wv = *(const uint4*)Wp;
  for (int kt = 0; kt < nk; ++kt) {
    *(uint4*)&As[srow * 32 + scol] = av;
    *(uint4*)&Bs[srow * 32 + scol] = wv;
    __syncthreads();
    if (kt + 1 < nk) {
      Ap += 32; Wp += 32;
      av = *(const uint4*)Ap;
      wv = *(const uint4*)Wp;
    }
    bf16x8 af = *(const bf16x8*)&As[aoff];
    bf16x8 b0 = *(const bf16x8*)&Bs[boff];
    bf16x8 b1 = *(const bf16x8*)&Bs[boff + 16 * 32];
    bf16x8 b2 = *(const bf16x8*)&Bs[boff + 32 * 32];
    bf16x8 b3 = *(const bf16x8*)&Bs[boff + 48 * 32];
    acc0 = __builtin_amdgcn_mfma_f32_16x16x32_bf16(af, b0, acc0, 0, 0, 0);
    acc1 = __builtin_amdgcn_mfma_f32_16x16x32_bf16(af, b1, acc1, 0, 0, 0);
    acc2 = __builtin_amdgcn_mfma_f32_16x16x32_bf16(af, b2, acc2, 0, 0, 0);
    acc3 = __builtin_amdgcn_mfma_f32_16x16x32_bf16(af, b3, acc3, 0, 0, 0);
    __syncthreads();
  }
  int mbase = m0 + w * 16 + quad * 4;
  if (mode == 3) {
    for (int r = 0; r < 4; ++r) {
      int row = mbase + r;
      float vals[4] = {acc0[r], acc1[r], acc2[r], acc3[r]};
      for (int nt = 0; nt < 4; ++nt)
        out0[(size_t)row * N + (n0 + nt * 16 + lm)] = f2bf(vals[nt]);
    }
  } else {
    bool isV = ((blockIdx.y & 1) == 1);
    int head = (n0 >> 7);
    size_t hb = (size_t)head << 17;
    if (isV) {
      // V -> fragment-linear V^T layout
      int dof[4];
#pragma unroll
      for (int nt = 0; nt < 4; ++nt) dof[nt] = voff_d(nt * 16 + lm);
      for (int r = 0; r < 4; ++r) {
        int s = mbase + r;
        size_t so = hb + voff_s(s);
        float vals[4] = {acc0[r], acc1[r], acc2[r], acc3[r]};
#pragma unroll
        for (int nt = 0; nt < 4; ++nt)
          out1[so + dof[nt]] = f2bf(vals[nt]);
      }
    } else {
      // K -> RoPE -> fragment-linear K layout
      int d0 = koff_d(lm), d1 = koff_d(lm + 16), d2 = koff_d(lm + 32), d3 = koff_d(lm + 48);
      float invf1 = __expf(-(float)lm * RLN);
      float invf2 = __expf(-(float)(lm + 16) * RLN);
      for (int r = 0; r < 4; ++r) {
        int s = mbase + r;
        float a0 = acc0[r], a1 = acc1[r], a2 = acc2[r], a3 = acc3[r];
        float s1, c1, s2, c2;
        sincosf((float)s * invf1, &s1, &c1);
        sincosf((float)s * invf2, &s2, &c2);
        size_t so = hb + koff_s(s);
        out0[so + d0] = f2bf(a0 * c1 - a2 * s1);
        out0[so + d2] = f2bf(a2 * c1 + a0 * s1);
        out0[so + d1] = f2bf(a1 * c2 - a3 * s2);
        out0[so + d3] = f2bf(a3 * c2 + a1 * s2);
      }
    }
  }
}

// ---------------- MFMA flash attention v3: S^T softmax, fragment-linear K/V ----------------
// grid (16, 64): block bx handles q-tiles {bx, 31-bx}. 4 waves, 16 q-rows/wave.
// No barriers. K/V fragment loads are contiguous 1KB wave loads.
__global__ __launch_bounds__(256, 4) void attn_v3(
    const u16* __restrict__ Qb, const u16* __restrict__ Kf,
    const u16* __restrict__ Vf, u16* __restrict__ attnb) {
  __shared__ __align__(16) u16 Ps[4 * 16 * 72];  // per-wave P, row stride 72 u16 (144B, 16B-aligned)
  int t = threadIdx.x;
  int w = t >> 6, L = t & 63;
  int lm = L & 15, quad = L >> 4;
  int bx = blockIdx.x, h = blockIdx.y, kvh = h >> 3;
  u16* pw = &Ps[w * 16 * 72];
  const u16* Kbase = Kf + ((size_t)kvh << 17) + L * 8;
  const u16* Vbase = Vf + ((size_t)kvh << 17) + L * 8;

  for (int ph = 0; ph < 2; ++ph) {
    int qt = ph ? (31 - bx) : bx;
    int q0 = qt * 64;
    // Q B-fragments: lane holds Q[q0+w*16+lm][quad*8+e] (halves 0/1)
    const u16* Qp = Qb + ((size_t)h * S_LEN + q0 + w * 16 + lm) * HD + quad * 8;
    bf16x8 qf0 = *(const bf16x8*)Qp;
    bf16x8 qf1 = *(const bf16x8*)(Qp + 32);
    f32x4 o[4] = {};
    float m_ = -3.0e38f, l_ = 0.f;

    for (int c = 0; c <= qt; ++c) {
      const u16* Kc = Kbase + (size_t)c * 4096;
      // ---- K fragments: contiguous 1KB wave loads ----
      bf16x8 kfa[4], kfb[4];
#pragma unroll
      for (int j = 0; j < 4; ++j) {
        kfa[j] = *(const bf16x8*)(Kc + j * 1024);
        kfb[j] = *(const bf16x8*)(Kc + j * 1024 + 512);
      }
      // ---- S^T = K Q^T : tile j rows kv=j*16+quad*4+r, col q=lm ----
      f32x4 st[4] = {};
#pragma unroll
      for (int j = 0; j < 4; ++j) {
        st[j] = __builtin_amdgcn_mfma_f32_16x16x32_bf16(kfa[j], qf0, st[j], 0, 0, 0);
        st[j] = __builtin_amdgcn_mfma_f32_16x16x32_bf16(kfb[j], qf1, st[j], 0, 0, 0);
      }
      // ---- V fragments issued now (consumed ~500cyc later) ----
      const u16* Vc = Vbase + (size_t)c * 4096;
      bf16x8 vfa[4], vfb[4];
#pragma unroll
      for (int j = 0; j < 4; ++j) {
        vfa[j] = *(const bf16x8*)(Vc + j * 1024);
        vfb[j] = *(const bf16x8*)(Vc + j * 1024 + 512);
      }
      // ---- causal mask on diagonal chunk ----
      // lane's q-row (local to the 64-row tile) is w*16+lm; kv local is kvb+r.
      // (R4 bug: compared against lm only -> waves 1-3 over-masked.)
      if (c == qt) {
        int qloc = w * 16 + lm;
#pragma unroll
        for (int j = 0; j < 4; ++j) {
          int kvb = j * 16 + quad * 4;
#pragma unroll
          for (int r = 0; r < 4; ++r)
            if (kvb + r > qloc) st[j][r] = -3.0e38f;
        }
      }
      // ---- online softmax: each lane owns 16 scores of q-row lm ----
      float mloc = -3.0e38f;
#pragma unroll
      for (int j = 0; j < 4; ++j)
        mloc = fmaxf(mloc, fmaxf(fmaxf(st[j][0], st[j][1]), fmaxf(st[j][2], st[j][3])));
      mloc = fmaxf(mloc, __shfl_xor(mloc, 16));
      mloc = fmaxf(mloc, __shfl_xor(mloc, 32));
      float mn = fmaxf(m_, mloc);
      float al = __expf(m_ - mn);
      m_ = mn;
      float sum = 0.f;
      u16* pws = pw + lm * 72;
#pragma unroll
      for (int j = 0; j < 4; ++j) {
        float p0 = __expf(st[j][0] - mn);
        float p1 = __expf(st[j][1] - mn);
        float p2 = __expf(st[j][2] - mn);
        float p3 = __expf(st[j][3] - mn);
        sum += (p0 + p1) + (p2 + p3);
        uint2 pk;
        pk.x = (u32)f2bf(p0) | ((u32)f2bf(p1) << 16);
        pk.y = (u32)f2bf(p2) | ((u32)f2bf(p3) << 16);
        *(uint2*)(pws + j * 16 + quad * 4) = pk;
      }
      l_ = l_ * al + sum;
      // ---- redistribute alpha to O's C-layout rows (quad*4+r) ----
      float a0 = __shfl(al, quad * 4 + 0);
      float a1 = __shfl(al, quad * 4 + 1);
      float a2 = __shfl(al, quad * 4 + 2);
      float a3 = __shfl(al, quad * 4 + 3);
#pragma unroll
      for (int j = 0; j < 4; ++j) {
        o[j][0] *= a0; o[j][1] *= a1; o[j][2] *= a2; o[j][3] *= a3;
      }
      // ---- P (A-layout) from LDS ----
      bf16x8 pa = *(const bf16x8*)(pw + lm * 72 + quad * 8);
      bf16x8 pb = *(const bf16x8*)(pw + lm * 72 + 32 + quad * 8);
      // ---- O += P V ----
#pragma unroll
      for (int j = 0; j < 4; ++j) {
        o[j] = __builtin_amdgcn_mfma_f32_16x16x32_bf16(pa, vfa[j], o[j], 0, 0, 0);
        o[j] = __builtin_amdgcn_mfma_f32_16x16x32_bf16(pb, vfb[j], o[j], 0, 0, 0);
      }
    }
    // ---- finalize ----
    l_ += __shfl_xor(l_, 16);
    l_ += __shfl_xor(l_, 32);
    float linv = 1.0f / l_;
    float li0 = __shfl(linv, quad * 4 + 0);
    float li1 = __shfl(linv, quad * 4 + 1);
    float li2 = __shfl(linv, quad * 4 + 2);
    float li3 = __shfl(linv, quad * 4 + 3);
#pragma unroll
    for (int r = 0; r < 4; ++r) {
      float lr = (r == 0) ? li0 : (r == 1) ? li1 : (r == 2) ? li2 : li3;
      int row = q0 + w * 16 + quad * 4 + r;
      u16* op = attnb + (size_t)row * NQD + h * HD;
      op[lm]      = f2bf(o[0][r] * lr);
      op[lm + 16] = f2bf(o[1][r] * lr);
      op[lm + 32] = f2bf(o[2][r] * lr);
      op[lm + 48] = f2bf(o[3][r] * lr);
    }
  }
}

extern "C" void kernel_launch(void* const* d_in, const int* in_sizes, int n_in,
                              void* d_out, int out_size, void* d_ws, size_t ws_size,
                              hipStream_t stream) {
  (void)in_sizes; (void)n_in; (void)out_size; (void)ws_size;
  const float* hidden = (const float*)d_in[0];
  // d_in[1] = attention_mask (exactly causal; handled analytically)
  const float* q_w    = (const float*)d_in[2];
  const float* q_b    = (const float*)d_in[3];
  const float* kv_a_w = (const float*)d_in[4];
  const float* kv_b_w = (const float*)d_in[5];
  const float* o_w    = (const float*)d_in[6];
  const float* o_b    = (const float*)d_in[7];

  char* ws = (char*)d_ws;
  u16* hb    = (u16*)(ws + 0);           // 2048x2880
  u16* qwb   = (u16*)(ws + 11796480);    // 4096x2880
  u16* kab   = (u16*)(ws + 35389440);    // 384x2880
  u16* kbb   = (u16*)(ws + 37601280);    // 1024x384
  u16* owb   = (u16*)(ws + 38387712);    // 2880x4096
  u16* Qb    = (u16*)(ws + 61980672);    // (64,2048,64) roped, pre-scaled 1/8
  u16* CKVb  = (u16*)(ws + 78757888);    // 2048x384
  u16* Kfb   = (u16*)(ws + 80330752);    // (8) fragment-linear K, 2MB
  u16* Vfb   = (u16*)(ws + 82427904);    // (8) fragment-linear V^T, 2MB
  u16* attnb = (u16*)(ws + 84525056);    // 2048x4096

  conv_f2b<<<(1474560 + 255) / 256, 256, 0, stream>>>(hidden, hb, 1474560);
  conv_f2b<<<(2949120 + 255) / 256, 256, 0, stream>>>(q_w, qwb, 2949120);
  conv_f2b<<<(276480 + 255) / 256, 256, 0, stream>>>(kv_a_w, kab, 276480);
  conv_f2b<<<(98304 + 255) / 256, 256, 0, stream>>>(kv_b_w, kbb, 98304);
  conv_f2b<<<(2949120 + 255) / 256, 256, 0, stream>>>(o_w, owb, 2949120);

  gemm128<<<dim3(16, 32), 256, 0, stream>>>(hb, qwb, q_b, H_DIM, Qb);
  gemm_bt<<<dim3(32, 6),  256, 0, stream>>>(hb, kab, S_LEN, RANKD, H_DIM, 3, CKVb, nullptr);
  gemm_bt<<<dim3(32, 16), 256, 0, stream>>>(CKVb, kbb, S_LEN, 1024, RANKD, 2, Kfb, Vfb);
  attn_v3<<<dim3(16, 64), 256, 0, stream>>>(Qb, Kfb, Vfb, attnb);
  gemm64<<<dim3(32, 23), 256, 0, stream>>>(attnb, owb, o_b, NQD, H_DIM, (float*)d_out);
}